// Round 5
// baseline (224.805 us; speedup 1.0000x reference)
//
#include <hip/hip_runtime.h>
#include <hip/hip_bf16.h>
#include <math.h>

#define B_     16
#define C_     256
#define H_     56
#define W_     56
#define HEADS_ 4
#define CPER_  64
#define R_     16
#define HW_    (H_*W_)      // 3136
#define BN_EPS_ 1e-5f
#define XPAD   58           // padded xc spatial dim (1-px halo, zero-filled)

typedef short bf16x8 __attribute__((ext_vector_type(8)));
typedef float f32x4  __attribute__((ext_vector_type(4)));

__device__ inline unsigned short f2bf(float f) {
    unsigned int u = __builtin_bit_cast(unsigned int, f);
    u += 0x7fffu + ((u >> 16) & 1u);          // RNE (finite inputs only)
    return (unsigned short)(u >> 16);
}
__device__ inline unsigned int pack2(float a, float b) {
    return (unsigned int)f2bf(a) | ((unsigned int)f2bf(b) << 16);
}

// ---------------- K1: BN+ReLU -> xnb (bf16, plane-major, coalesced) + exact fp32 pool --
__global__ __launch_bounds__(256) void k_bn(
    const float* __restrict__ x,
    const float* __restrict__ gamma, const float* __restrict__ beta,
    const float* __restrict__ mean,  const float* __restrict__ var,
    unsigned int* __restrict__ xnb, float* __restrict__ xavg)
{
    int plane = blockIdx.x;                   // b*256 + c
    int c = plane & (C_ - 1);
    int tid = threadIdx.x;
    float s = gamma[c] * rsqrtf(var[c] + BN_EPS_);
    float t = fmaf(-mean[c], s, beta[c]);
    const float4* xp = (const float4*)(x + (size_t)plane * HW_);
    uint2* xo = (uint2*)(xnb + (size_t)plane * (HW_ / 2));
    float sum = 0.f;
    for (int i = tid; i < HW_ / 4; i += 256) {    // 784 float4
        float4 v = xp[i];
        float a0 = fmaxf(fmaf(v.x, s, t), 0.f);
        float a1 = fmaxf(fmaf(v.y, s, t), 0.f);
        float a2 = fmaxf(fmaf(v.z, s, t), 0.f);
        float a3 = fmaxf(fmaf(v.w, s, t), 0.f);
        sum += a0 + a1 + a2 + a3;
        uint2 o; o.x = pack2(a0, a1); o.y = pack2(a2, a3);
        xo[i] = o;
    }
    for (int off = 32; off; off >>= 1) sum += __shfl_down(sum, off, 64);
    __shared__ float sred[4];
    int lane = tid & 63, wv = tid >> 6;
    if (lane == 0) sred[wv] = sum;
    __syncthreads();
    if (tid == 0) xavg[plane] = (sred[0] + sred[1] + sred[2] + sred[3]) * (1.f / HW_);
}

// ---------------- K2: SE gate, exact rank-k threshold, compaction, lasso ---------------
__global__ __launch_bounds__(256) void k_se(
    const float* __restrict__ xavg,
    const float* __restrict__ fc1, const float* __restrict__ fc2,
    const float* __restrict__ fc2b, const int* __restrict__ kptr,
    float* __restrict__ maskc, int* __restrict__ aidx64,
    int* __restrict__ act_cnt, float* __restrict__ lasso)
{
    int hb = blockIdx.x;              // h*B + b
    int h = hb / B_, b = hb - h * B_;
    int tid = threadIdx.x;            // = channel c

    __shared__ float sav[C_], sy1[R_], smask[C_], sred[4], sthr;
    __shared__ int scnt, s_ord[C_];

    sav[tid] = xavg[b * C_ + tid];
    if (tid == 0) scnt = 0;
    __syncthreads();

    if (tid < R_) {
        const float* w = fc1 + (size_t)(h * R_ + tid) * C_;
        float acc = 0.f;
        for (int c2 = 0; c2 < C_; ++c2) acc = fmaf(sav[c2], w[c2], acc);
        sy1[tid] = fmaxf(acc, 0.f);
    }
    __syncthreads();

    const float* w2 = fc2 + (size_t)(h * C_ + tid) * R_;
    float acc = fc2b[h * C_ + tid];
    for (int r = 0; r < R_; ++r) acc = fmaf(sy1[r], w2[r], acc);
    float m = fmaxf(acc, 0.f);
    smask[tid] = m;
    __syncthreads();

    float ls = m;
    for (int off = 32; off > 0; off >>= 1) ls += __shfl_down(ls, off, 64);
    int lane = tid & 63, wv = tid >> 6;
    if (lane == 0) sred[wv] = ls;

    int cl = 0, ce = 0;
    for (int j = 0; j < C_; ++j) {
        float vj = smask[j];
        cl += (vj < m);
        ce += (vj == m);
    }
    if (tid == 0) sthr = -1e30f;
    __syncthreads();
    int k = kptr[0];
    if (k > 0 && cl <= k - 1 && (k - 1) < cl + ce) sthr = m;  // unique writer value
    __syncthreads();

    float thr = sthr;
    float mc = (m <= thr) ? 0.f : m;
    maskc[hb * C_ + tid] = mc;
    if (mc != 0.f) {
        int p = atomicAdd(&scnt, 1);          // order-free (all consumers share the list)
        s_ord[p] = tid;
    }
    __syncthreads();
    if (tid < 64) aidx64[hb * 64 + tid] = (tid < scnt) ? s_ord[tid] : 0;  // zero-padded
    if (tid == 0) {
        act_cnt[hb] = scnt;
        atomicAdd(lasso, (sred[0] + sred[1] + sred[2] + sred[3]) * (1.f / (B_ * C_)));
    }
}

// ---------------- K2c: compact+mask weights direct from conv_w -> Wc[hb][t][j][c'] -----
// conv_w is 2.36 MB -> L2-resident after first touch; j is wave-uniform so the gather
// is 64 scattered 4B reads in a 9KB window (L2). Write coalesced. Kills k_wt2.
__global__ __launch_bounds__(256) void k_wgather(
    const float* __restrict__ convw, const float* __restrict__ maskc,
    const int* __restrict__ aidx64, const int* __restrict__ acnt,
    short* __restrict__ Wc)
{
    int t = blockIdx.x, hb = blockIdx.y;
    int h = hb >> 4;
    int tid = threadIdx.x;
    int cnt = acnt[hb];
    __shared__ int s_act[64];
    __shared__ float s_mv[64];
    if (tid < 64) {
        int a = aidx64[hb * 64 + tid];
        s_act[tid] = a;
        s_mv[tid]  = (tid < cnt) ? maskc[hb * C_ + a] : 0.f;   // zero-pad kills c'>=cnt
    }
    __syncthreads();
    short* wdst = Wc + (size_t)(hb * 9 + t) * (CPER_ * 64);
    for (int it = 0; it < 16; ++it) {
        int e = it * 256 + tid;
        int cp = e & 63, j = e >> 6;              // j wave-uniform
        float v = convw[((size_t)((h * CPER_ + j) * C_ + s_act[cp])) * 9 + t] * s_mv[cp];
        wdst[j * 64 + cp] = (short)f2bf(v);
    }
}

// ---------------- K2d: re-layout xnb -> xc[hb][58][58][64] (padded, compacted) ---------
// Fully coalesced: read 64 channel-rows (112B each) -> LDS transpose -> write pixel-major.
__global__ __launch_bounds__(256) void k_bnc2(
    const unsigned short* __restrict__ xnb, const int* __restrict__ aidx64,
    short* __restrict__ xc)
{
    int y = blockIdx.x, hb = blockIdx.y;
    int b = hb & 15;
    int tid = threadIdx.x;
    __shared__ unsigned short T[64 * 58];     // [ch][px], row stride 58 (even, banks spread)
    __shared__ int s_act[64];
    if (tid < 64) s_act[tid] = aidx64[hb * 64 + tid];
    __syncthreads();

    const unsigned int* xs = (const unsigned int*)xnb;
    for (int i = tid; i < 64 * 28; i += 256) {    // 7 iters, 2 px per u32
        int ch = i / 28, d = i - ch * 28;
        unsigned int v = xs[(size_t)(b * C_ + s_act[ch]) * (HW_ / 2) + y * (W_ / 2) + d];
        *(unsigned int*)&T[ch * 58 + 2 * d] = v;  // 4B-aligned (58 even)
    }
    __syncthreads();

    unsigned int* xcd = (unsigned int*)(xc + (size_t)hb * XPAD * XPAD * 64);
    int row = (y + 1) * XPAD;
    for (int i = tid; i < W_ * 32; i += 256) {    // 7 iters
        int px = i >> 5, dd = i & 31;
        unsigned int lo = T[(2 * dd)     * 58 + px];
        unsigned int hi = T[(2 * dd + 1) * 58 + px];
        xcd[(size_t)(row + px + 1) * 32 + dd] = lo | (hi << 16);
    }
    // halo: left/right column of this row; top/bottom rows by edge blocks
    if (tid < 64) xcd[(size_t)(row + (tid >> 5) * (XPAD - 1)) * 32 + (tid & 31)] = 0;
    if (y == 0)      for (int i = tid; i < XPAD * 32; i += 256) xcd[i] = 0;
    if (y == H_ - 1) for (int i = tid; i < XPAD * 32; i += 256)
        xcd[(size_t)(XPAD - 1) * XPAD * 32 + i] = 0;
}

// ---------------- K3: implicit-GEMM bf16 MFMA conv — no LDS, no barriers ---------------
// Per wave: acc[4jt][4xt], K=64 (2 chunks). Stage s+1's 8 loads (4 A + 4 B, all 16B
// coalesced, L2-resident working set) issue before stage s's MFMAs via ping-pong regs;
// tap loop is a REAL loop so the compiler can't bulk-hoist. Waves free-run (AITER-style
// fine-grained vmcnt instead of barrier drains). Padded xc -> no bounds predicates.
#define LOADA(dst, T, C0) { const short* wp_ = Wh + (T) * 4096 + m * 64 + (C0) + q * 8; \
    _Pragma("unroll") for (int jt_ = 0; jt_ < 4; ++jt_) \
        dst[jt_] = *(const bf16x8*)(wp_ + jt_ * 1024); }

#define LOADB(dst, DY, DX, C0) { int rb_ = (yrow + (DY) + 1) * XPAD; \
    _Pragma("unroll") for (int xt_ = 0; xt_ < 4; ++xt_) { \
        int gx_ = xt_ * 16 + m + (DX) + 1; gx_ = gx_ > 57 ? 57 : gx_; \
        dst[xt_] = *(const bf16x8*)(xb + (size_t)(rb_ + gx_) * 64 + (C0) + q * 8); } }

#define MFMA16(A_, B_v) _Pragma("unroll") for (int jt_ = 0; jt_ < 4; ++jt_) \
    _Pragma("unroll") for (int xt_ = 0; xt_ < 4; ++xt_) \
        acc[jt_][xt_] = __builtin_amdgcn_mfma_f32_16x16x32_bf16(A_[jt_], B_v[xt_], acc[jt_][xt_], 0, 0, 0);

__global__ __launch_bounds__(256, 3) void k_conv(
    const short* __restrict__ xc, const short* __restrict__ Wc,
    float* __restrict__ out)
{
    int g = blockIdx.x;
    int vx = g & 7, r = g >> 3;               // XCD-local hb window (Wc/xc L2-resident)
    int hb = vx * 8 + r / 14;
    int band = r - (r / 14) * 14;
    int h = hb >> 4, b = hb & 15;
    int tid = threadIdx.x, lane = tid & 63, wv = tid >> 6;
    int m = lane & 15, q = lane >> 4;
    int yrow = band * 4 + wv;

    const short* Wh = Wc + (size_t)hb * 9 * 4096;
    const short* xb = xc + (size_t)hb * XPAD * XPAD * 64;

    f32x4 acc[4][4];
    #pragma unroll
    for (int i = 0; i < 4; ++i)
        #pragma unroll
        for (int j = 0; j < 4; ++j)
            #pragma unroll
            for (int rr = 0; rr < 4; ++rr) acc[i][j][rr] = 0.f;

    bf16x8 Ac[4], Bc[4], An[4], Bn[4];
    int dy = -1, dx = -1;
    LOADA(Ac, 0, 0)
    LOADB(Bc, dy, dx, 0)

    for (int t = 0; t < 9; ++t) {
        int dxn = (dx == 1) ? -1 : dx + 1;        // next tap geometry (wave-uniform SALU)
        int dyn = (dx == 1) ? dy + 1 : dy;
        LOADA(An, t, 32)                          // stage (t, c0=32) in flight
        LOADB(Bn, dy, dx, 32)
        MFMA16(Ac, Bc)                            // compute (t, c0=0)
        if (t < 8) {
            LOADA(Ac, (t + 1), 0)                 // stage (t+1, c0=0) in flight
            LOADB(Bc, dyn, dxn, 0)
        }
        MFMA16(An, Bn)                            // compute (t, c0=32)
        dy = dyn; dx = dxn;
    }

    #pragma unroll
    for (int xt = 0; xt < 4; ++xt) {
        int xx = xt * 16 + m;
        if (xx < W_) {
            #pragma unroll
            for (int jt = 0; jt < 4; ++jt)
                #pragma unroll
                for (int rr = 0; rr < 4; ++rr) {
                    int j = jt * 16 + q * 4 + rr;         // D: row = quad*4 + reg
                    int oc = j * HEADS_ + h;              // head interleave
                    out[(((size_t)b * C_ + oc) * H_ + yrow) * W_ + xx] = acc[jt][xt][rr];
                }
        }
    }
}

// ---------------- launch ----------------------------------------------------------------
extern "C" void kernel_launch(void* const* d_in, const int* in_sizes, int n_in,
                              void* d_out, int out_size, void* d_ws, size_t ws_size,
                              hipStream_t stream)
{
    const float* x     = (const float*)d_in[0];
    const float* gamma = (const float*)d_in[1];
    const float* beta  = (const float*)d_in[2];
    const float* mean  = (const float*)d_in[3];
    const float* var   = (const float*)d_in[4];
    const float* fc1   = (const float*)d_in[5];
    const float* fc2   = (const float*)d_in[6];
    const float* fc2b  = (const float*)d_in[7];
    const float* convw = (const float*)d_in[8];
    const int*   kptr  = (const int*)d_in[9];

    float* out   = (float*)d_out;
    float* lasso = out + (size_t)B_ * C_ * HW_;

    char* ws = (char*)d_ws;
    size_t off = 0;
    unsigned int* xnb = (unsigned int*)(ws + off); off += (size_t)B_ * C_ * HW_ * 2;      // 25.7 MB
    off = (off + 255) & ~(size_t)255;
    short* xc    = (short*)(ws + off); off += (size_t)HEADS_ * B_ * XPAD * XPAD * 64 * 2; // 27.6 MB
    off = (off + 255) & ~(size_t)255;
    float* xavg  = (float*)(ws + off); off += (size_t)B_ * C_ * 4;
    float* maskc = (float*)(ws + off); off += (size_t)HEADS_ * B_ * C_ * 4;
    int*   aidx64= (int*)  (ws + off); off += (size_t)HEADS_ * B_ * 64 * 4;
    int*   acnt  = (int*)  (ws + off); off += (size_t)HEADS_ * B_ * 4;
    off = (off + 255) & ~(size_t)255;
    short* Wc    = (short*)(ws + off); off += (size_t)HEADS_ * B_ * 9 * CPER_ * 64 * 2;   // 4.72 MB

    hipMemsetAsync(lasso, 0, 4, stream);

    k_bn<<<B_ * C_, 256, 0, stream>>>(x, gamma, beta, mean, var, xnb, xavg);
    k_se<<<HEADS_ * B_, 256, 0, stream>>>(xavg, fc1, fc2, fc2b, kptr,
                                          maskc, aidx64, acnt, lasso);
    k_wgather<<<dim3(9, HEADS_ * B_), 256, 0, stream>>>(convw, maskc, aidx64, acnt, Wc);
    k_bnc2<<<dim3(H_, HEADS_ * B_), 256, 0, stream>>>((const unsigned short*)xnb, aidx64, xc);
    k_conv<<<HEADS_ * B_ * (H_ / 4), 256, 0, stream>>>(xc, Wc, out);
}